// Round 11
// baseline (1521.253 us; speedup 1.0000x reference)
//
#include <hip/hip_runtime.h>

// ---------------------------------------------------------------------------
// Transformer forward, MI355X gfx950. bf16 MFMA compute, fp32 accum/output.
//   activations: row = b*S + s (M = 2048 rows)
//   vT buffer:   [32 bh][64 d][1024 t] bf16 (V transposed, written by kqv GEMM)
// Layer GEMMs read B weights DIRECTLY as fp32 (reg-staged, converted in
// flight) -- once-used weights get no bf16 round-trip. kqv GEMM fuses the
// per-head K2/Q2 second MLP. Vocab GEMM: 256x256 BK=64 4-phase template with
// bf16 wpred (small cvt kernel covers k2/q2/predw only).
// Attention: no-max softmax + K/V register double-buffer.
// ---------------------------------------------------------------------------

typedef __attribute__((ext_vector_type(8))) short bf16x8;
typedef __attribute__((ext_vector_type(4))) float f32x4;

#define L_ 8
#define S_ 1024
#define E_ 1024
#define B_ 2
#define H_ 16
#define V_ 32000
#define M_ 2048  // B*S

__device__ __forceinline__ unsigned short f2b(float f) {
  union { float f; unsigned int u; } v; v.f = f;
  unsigned int r = v.u + 0x7FFFu + ((v.u >> 16) & 1u);
  return (unsigned short)(r >> 16);
}

__device__ __forceinline__ bf16x8 pack8(float4 lo, float4 hi) {
  bf16x8 v;
  v[0] = (short)f2b(lo.x); v[1] = (short)f2b(lo.y);
  v[2] = (short)f2b(lo.z); v[3] = (short)f2b(lo.w);
  v[4] = (short)f2b(hi.x); v[5] = (short)f2b(hi.y);
  v[6] = (short)f2b(hi.z); v[7] = (short)f2b(hi.w);
  return v;
}

#define GLDS16(gptr, lptr)                                                            \
  __builtin_amdgcn_global_load_lds(                                                   \
      (const __attribute__((address_space(1))) unsigned int*)(gptr),                  \
      (__attribute__((address_space(3))) unsigned int*)(lptr), 16, 0, 0)

// ---------------- small weight conversion (k2, q2, predw only) -------------
__global__ void cvt3_kernel(const float* __restrict__ k2w, const float* __restrict__ q2w,
                            const float* __restrict__ predw,
                            unsigned short* __restrict__ wk2, unsigned short* __restrict__ wq2,
                            unsigned short* __restrict__ wpred) {
  size_t u = (size_t)blockIdx.x * 256 + threadIdx.x;
  const float* src; unsigned short* dst;
  if (u < 131072)      { size_t e = u * 4;            src = k2w + e;   dst = wk2 + e; }
  else if (u < 262144) { size_t e = (u - 131072) * 4; src = q2w + e;   dst = wq2 + e; }
  else                 { size_t e = (u - 262144) * 4; src = predw + e; dst = wpred + e; }
  float4 v = *(const float4*)src;
  dst[0] = f2b(v.x); dst[1] = f2b(v.y); dst[2] = f2b(v.z); dst[3] = f2b(v.w);
}

__global__ void biascat_kernel(const float* __restrict__ k1b, const float* __restrict__ q1b,
                               const float* __restrict__ vb, float* __restrict__ bcat) {
  int i = blockIdx.x * 256 + threadIdx.x;  // 8*3072 exact
  int l = i / 3072, j = i - l * 3072;
  float v;
  if (j < 1024)      v = k1b[l * 1024 + j];
  else if (j < 2048) v = q1b[l * 1024 + j - 1024];
  else               v = vb [l * 1024 + j - 2048];
  bcat[i] = v;
}

// ---------------- embedding ----------------
__global__ void embed_kernel(const int* __restrict__ tokens, const float* __restrict__ emb,
                             const float* __restrict__ pe, float* __restrict__ x32,
                             unsigned short* __restrict__ xb) {
  int row = blockIdx.x;           // b*S + s
  int s = row & (S_ - 1);
  int e0 = threadIdx.x * 4;
  int tok = tokens[row];
  float4 ev = *(const float4*)(emb + (size_t)tok * E_ + e0);
  float4 pv = *(const float4*)(pe + (size_t)s * E_ + e0);
  float4 v; v.x = ev.x + pv.x; v.y = ev.y + pv.y; v.z = ev.z + pv.z; v.w = ev.w + pv.w;
  *(float4*)(x32 + (size_t)row * E_ + e0) = v;
  ushort4 o; o.x = f2b(v.x); o.y = f2b(v.y); o.z = f2b(v.z); o.w = f2b(v.w);
  *(ushort4*)(xb + (size_t)row * E_ + e0) = o;
}

// ---------------- m97-style GEMM: C = act(A * W^T + bias) ----------------
// A: bf16 via global_load_lds. W: fp32, reg-staged + converted in flight.
// Segment select: seg = col0>>10 picks W0/W1/W2 (kqv: k1|q1|v; else W0).
// K2Q2: blocks with col0<2048 route relu'd output through LDS into the
// per-head second MLP (k2/q2), writing kbuf/qbuf.
template <int BM, int BN, int RELU, int OBF, int OF32, int VT, int K2Q2>
__global__ __launch_bounds__(256) void gemm97(
    const unsigned short* __restrict__ A,
    const float* __restrict__ W0, const float* __restrict__ W1, const float* __restrict__ W2,
    const float* __restrict__ bias, unsigned short* __restrict__ Cb,
    float* __restrict__ Cf, unsigned short* __restrict__ vTp,
    const unsigned short* __restrict__ wk2p, const unsigned short* __restrict__ wq2p,
    const float* __restrict__ k2bp, const float* __restrict__ q2bp,
    unsigned short* __restrict__ kbufp, unsigned short* __restrict__ qbufp,
    int K, int N, int reluN) {
  constexpr int AR = BM / 64;
  constexpr int BR = BN / 64;
  constexpr int FM = BM / 32;
  constexpr int FN = BN / 32;
  __shared__ __align__(16) unsigned short sA[BM * 32];
  __shared__ __align__(16) unsigned short sB[BN * 32];
  __shared__ __align__(16) unsigned short sC[K2Q2 ? 128 * 136 : 1];  // padded
  const int tid = threadIdx.x;
  const int lane = tid & 63, wave = tid >> 6;
  const int l16 = lane & 15, lhi = lane >> 4;

  const int gx = gridDim.x, nwg = gx * gridDim.y;
  int o = blockIdx.y * gx + blockIdx.x;
  int wg = ((nwg & 7) == 0) ? ((o & 7) * (nwg >> 3) + (o >> 3)) : o;
  const int row0 = (wg % gx) * BM, col0 = (wg / gx) * BN;

  const int wm = (wave >> 1) * (BM / 2), wn = (wave & 1) * (BN / 2);

  const int srow = wave * 16 + (lane >> 2);
  const int scol = ((lane & 3) ^ ((lane >> 3) & 3)) * 8;   // chunk ^ ((row>>1)&3)
  const int cx = (lhi ^ ((l16 >> 1) & 3)) * 8;

  // fp32 weight segment (uniform per block; BN<=128 so no boundary crossing)
  const int seg = col0 >> 10;
  const float* Wp = (seg == 0) ? W0 : (seg == 1) ? W1 : W2;
  const int nb0 = col0 - (seg << 10);

  f32x4 acc[FM][FN] = {};

  for (int k0 = 0; k0 < K; k0 += 32) {
    // B: fp32 reg loads (issued first to overlap with A glds)
    float4 blo[BR], bhi[BR];
#pragma unroll
    for (int r = 0; r < BR; r++) {
      const float* src = Wp + (size_t)(nb0 + r * 64 + srow) * K + k0 + scol;
      blo[r] = *(const float4*)src;
      bhi[r] = *(const float4*)(src + 4);
    }
#pragma unroll
    for (int r = 0; r < AR; r++)
      GLDS16(A + (size_t)(row0 + r * 64 + srow) * K + k0 + scol,
             sA + r * 2048 + wave * 512);
#pragma unroll
    for (int r = 0; r < BR; r++)
      *(bf16x8*)(sB + r * 2048 + wave * 512 + lane * 8) = pack8(blo[r], bhi[r]);
    __syncthreads();

    bf16x8 af[FM], bf[FN];
#pragma unroll
    for (int i = 0; i < FM; i++)
      af[i] = *(const bf16x8*)(sA + (wm + i * 16 + l16) * 32 + cx);
#pragma unroll
    for (int j = 0; j < FN; j++)
      bf[j] = *(const bf16x8*)(sB + (wn + j * 16 + l16) * 32 + cx);
#pragma unroll
    for (int i = 0; i < FM; i++)
#pragma unroll
      for (int j = 0; j < FN; j++)
        acc[i][j] = __builtin_amdgcn_mfma_f32_16x16x32_bf16(bf[j], af[i], acc[i][j], 0, 0, 0);
    __syncthreads();
  }

  if (K2Q2 && col0 < 2048) {
    // ---- stage relu'd k1/q1 output into padded LDS ----
#pragma unroll
    for (int j = 0; j < FN; j++) {
      const int colb = wn + j * 16 + lhi * 4;
      const float4 bv = *(const float4*)(bias + col0 + colb);
#pragma unroll
      for (int i = 0; i < FM; i++) {
        const int lrow = wm + i * 16 + l16;
        ushort4 ob;
        ob.x = f2b(fmaxf(acc[i][j][0] + bv.x, 0.f));
        ob.y = f2b(fmaxf(acc[i][j][1] + bv.y, 0.f));
        ob.z = f2b(fmaxf(acc[i][j][2] + bv.z, 0.f));
        ob.w = f2b(fmaxf(acc[i][j][3] + bv.w, 0.f));
        *(ushort4*)(sC + lrow * 136 + colb) = ob;
      }
    }
    __syncthreads();
    // ---- per-head second MLP: wave (wave>>1) rows, head (wave&1) ----
    const int which = (col0 >= 1024) ? 1 : 0;
    const int h = ((col0 & 1023) >> 6) + (wave & 1);
    const unsigned short* W2b = (which ? wq2p : wk2p) + h * 4096;
    const float* b2 = (which ? q2bp : k2bp) + h * 64;
    unsigned short* outp = (which ? qbufp : kbufp) + h * 64;
    const int r0 = (wave >> 1) * 64;
    f32x4 acc2[4][4] = {};
#pragma unroll
    for (int ks = 0; ks < 2; ks++) {
      bf16x8 bfr[4], af2[4];
#pragma unroll
      for (int j = 0; j < 4; j++)
        bfr[j] = *(const bf16x8*)(W2b + (j * 16 + l16) * 64 + ks * 32 + (lhi << 3));
#pragma unroll
      for (int i = 0; i < 4; i++)
        af2[i] = *(const bf16x8*)(sC + (r0 + i * 16 + l16) * 136 + (wave & 1) * 64 +
                                  ks * 32 + (lhi << 3));
#pragma unroll
      for (int i = 0; i < 4; i++)
#pragma unroll
        for (int j = 0; j < 4; j++)
          acc2[i][j] = __builtin_amdgcn_mfma_f32_16x16x32_bf16(bfr[j], af2[i], acc2[i][j], 0, 0, 0);
    }
#pragma unroll
    for (int j = 0; j < 4; j++) {
      const float4 bv = *(const float4*)(b2 + j * 16 + lhi * 4);
#pragma unroll
      for (int i = 0; i < 4; i++) {
        const int row = row0 + r0 + i * 16 + l16;
        ushort4 ob;
        ob.x = f2b(fmaxf(acc2[i][j][0] + bv.x, 0.f));
        ob.y = f2b(fmaxf(acc2[i][j][1] + bv.y, 0.f));
        ob.z = f2b(fmaxf(acc2[i][j][2] + bv.z, 0.f));
        ob.w = f2b(fmaxf(acc2[i][j][3] + bv.w, 0.f));
        *(ushort4*)(outp + (size_t)row * 1024 + j * 16 + lhi * 4) = ob;
      }
    }
  } else {
#pragma unroll
    for (int j = 0; j < FN; j++) {
      const int colb = col0 + wn + j * 16 + lhi * 4;
      const float4 bv = *(const float4*)(bias + colb);
      const bool dorelu = (RELU == 1) || (RELU == 2 && colb < reluN);
#pragma unroll
      for (int i = 0; i < FM; i++) {
        const int row = row0 + wm + i * 16 + l16;
        float v0 = acc[i][j][0] + bv.x, v1 = acc[i][j][1] + bv.y;
        float v2 = acc[i][j][2] + bv.z, v3 = acc[i][j][3] + bv.w;
        if (dorelu) {
          v0 = fmaxf(v0, 0.f); v1 = fmaxf(v1, 0.f);
          v2 = fmaxf(v2, 0.f); v3 = fmaxf(v3, 0.f);
        }
        if (OBF) {
          ushort4 ob; ob.x = f2b(v0); ob.y = f2b(v1); ob.z = f2b(v2); ob.w = f2b(v3);
          *(ushort4*)(Cb + (size_t)row * N + colb) = ob;
        }
        if (OF32) {
          float4 of; of.x = v0; of.y = v1; of.z = v2; of.w = v3;
          *(float4*)(Cf + (size_t)row * N + colb) = of;
        }
        if (VT) {
          if (colb - lhi * 4 >= 2048) {
            const int hd0 = colb - 2048;
            const int bq = row >> 10, s = row & 1023;
            unsigned short* vr = vTp + ((size_t)(bq << 10) + hd0) * 1024 + s;
            vr[0] = f2b(v0); vr[1024] = f2b(v1); vr[2048] = f2b(v2); vr[3072] = f2b(v3);
          }
        }
      }
    }
  }
}

// ---------------- vocab GEMM: 256x256, BK=64, 4-phase/K-tile template -------
__global__ __launch_bounds__(512, 1) void gemm256_8p(
    const unsigned short* __restrict__ A, const unsigned short* __restrict__ W,
    const float* __restrict__ bias, float* __restrict__ Cf) {
  constexpr int NT = 16;               // K=1024 / BK=64
  __shared__ __align__(16) unsigned short sA[2][2][8192];
  __shared__ __align__(16) unsigned short sB[2][2][8192];
  const int tid = threadIdx.x;
  const int lane = tid & 63, wave = tid >> 6;
  const int l16 = lane & 15, lhi = lane >> 4;
  const int wr = wave >> 2, wc = wave & 3;   // 2 x 4 wave grid, tile 128x64

  const int o = blockIdx.x;
  const int wg = (o & 7) * 125 + (o >> 3);   // bijective XCD chunking
  const int row0 = (wg & 7) * 256;
  const int col0 = (wg >> 3) * 256;

  const int srow = tid >> 2;                              // staging row (128)
  const int sk   = ((tid & 3) ^ ((tid >> 3) & 3)) * 8;    // chunk ^ ((row>>1)&3)
  const int rsw  = (l16 >> 1) & 3;                        // read-side row bits

  f32x4 acc[2][4][4] = {};

  auto stageA = [&](int kt, int s) {
    const int buf = kt & 1;
    const int kg = kt * 64 + s * 32 + sk;
#pragma unroll
    for (int i = 0; i < 2; i++)
      GLDS16(A + (size_t)(row0 + i * 128 + srow) * 1024 + kg,
             &sA[buf][s][i * 4096 + wave * 512]);
  };
  auto stageB = [&](int kt, int s) {
    const int buf = kt & 1;
    const int kg = kt * 64 + s * 32 + sk;
#pragma unroll
    for (int i = 0; i < 2; i++)
      GLDS16(W + (size_t)(col0 + i * 128 + srow) * 1024 + kg,
             &sB[buf][s][i * 4096 + wave * 512]);
  };

  stageA(0, 0); stageB(0, 0); stageA(0, 1); stageB(0, 1);

  bf16x8 af[4], bf[4];
  for (int kt = 0; kt < NT; kt++) {
    const int buf = kt & 1;
    const bool more = (kt + 1 < NT);

    // ---- phase 0: (rh0, ks0) ----
    asm volatile("s_waitcnt vmcnt(4)" ::: "memory");
    __builtin_amdgcn_s_barrier();
    __builtin_amdgcn_sched_barrier(0);
#pragma unroll
    for (int j = 0; j < 4; j++)
      bf[j] = *(const bf16x8*)(&sB[buf][0][(wc * 64 + j * 16 + l16) * 32 + ((lhi ^ rsw) << 3)]);
#pragma unroll
    for (int i = 0; i < 4; i++)
      af[i] = *(const bf16x8*)(&sA[buf][0][(wr * 128 + i * 16 + l16) * 32 + ((lhi ^ rsw) << 3)]);
    if (more) stageA(kt + 1, 0);
    asm volatile("s_waitcnt lgkmcnt(0)" ::: "memory");
    __builtin_amdgcn_sched_barrier(0);
    __builtin_amdgcn_s_setprio(1);
#pragma unroll
    for (int i = 0; i < 4; i++)
#pragma unroll
      for (int j = 0; j < 4; j++)
        acc[0][i][j] = __builtin_amdgcn_mfma_f32_16x16x32_bf16(bf[j], af[i], acc[0][i][j], 0, 0, 0);
    __builtin_amdgcn_s_setprio(0);
    __builtin_amdgcn_s_barrier();

    // ---- phase 1: (rh1, ks0) ----
#pragma unroll
    for (int i = 0; i < 4; i++)
      af[i] = *(const bf16x8*)(&sA[buf][0][(wr * 128 + 64 + i * 16 + l16) * 32 + ((lhi ^ rsw) << 3)]);
    if (more) stageB(kt + 1, 0);
    asm volatile("s_waitcnt lgkmcnt(0)" ::: "memory");
    __builtin_amdgcn_sched_barrier(0);
    __builtin_amdgcn_s_setprio(1);
#pragma unroll
    for (int i = 0; i < 4; i++)
#pragma unroll
      for (int j = 0; j < 4; j++)
        acc[1][i][j] = __builtin_amdgcn_mfma_f32_16x16x32_bf16(bf[j], af[i], acc[1][i][j], 0, 0, 0);
    __builtin_amdgcn_s_setprio(0);
    __builtin_amdgcn_s_barrier();

    // ---- phase 2: (rh0, ks1) ----
    if (kt == NT - 1) { asm volatile("s_waitcnt vmcnt(0)" ::: "memory"); }
    else              { asm volatile("s_waitcnt vmcnt(4)" ::: "memory"); }
    __builtin_amdgcn_s_barrier();
    __builtin_amdgcn_sched_barrier(0);
#pragma unroll
    for (int j = 0; j < 4; j++)
      bf[j] = *(const bf16x8*)(&sB[buf][1][(wc * 64 + j * 16 + l16) * 32 + ((lhi ^ rsw) << 3)]);
#pragma unroll
    for (int i = 0; i < 4; i++)
      af[i] = *(const bf16x8*)(&sA[buf][1][(wr * 128 + i * 16 + l16) * 32 + ((lhi ^ rsw) << 3)]);
    if (more) stageA(kt + 1, 1);
    asm volatile("s_waitcnt lgkmcnt(0)" ::: "memory");
    __builtin_amdgcn_sched_barrier(0);
    __builtin_amdgcn_s_setprio(1);
#pragma unroll
    for (int i = 0; i < 4; i++)
#pragma unroll
      for (int j = 0; j < 4; j++)
        acc[0][i][j] = __builtin_amdgcn_mfma_f32_16x16x32_bf16(bf[j], af[i], acc[0][i][j], 0, 0, 0);
    __builtin_amdgcn_s_setprio(0);
    __builtin_amdgcn_s_barrier();

    // ---- phase 3: (rh1, ks1) ----
#pragma unroll
    for (int i = 0; i < 4; i++)
      af[i] = *(const bf16x8*)(&sA[buf][1][(wr * 128 + 64 + i * 16 + l16) * 32 + ((lhi ^ rsw) << 3)]);
    if (more) stageB(kt + 1, 1);
    asm volatile("s_waitcnt lgkmcnt(0)" ::: "memory");
    __builtin_amdgcn_sched_barrier(0);
    __builtin_amdgcn_s_setprio(1);
#pragma unroll
    for (int i = 0; i < 4; i++)
#pragma unroll
      for (int j = 0; j < 4; j++)
        acc[1][i][j] = __builtin_amdgcn_mfma_f32_16x16x32_bf16(bf[j], af[i], acc[1][i][j], 0, 0, 0);
    __builtin_amdgcn_s_setprio(0);
    __builtin_amdgcn_s_barrier();
  }

#pragma unroll
  for (int rh = 0; rh < 2; rh++) {
#pragma unroll
    for (int j = 0; j < 4; j++) {
      const int colb = col0 + wc * 64 + j * 16 + lhi * 4;
      const float4 bv = *(const float4*)(bias + colb);
#pragma unroll
      for (int i = 0; i < 4; i++) {
        const int row = row0 + wr * 128 + rh * 64 + i * 16 + l16;
        float4 of;
        of.x = acc[rh][i][j][0] + bv.x; of.y = acc[rh][i][j][1] + bv.y;
        of.z = acc[rh][i][j][2] + bv.z; of.w = acc[rh][i][j][3] + bv.w;
        *(float4*)(Cf + (size_t)row * V_ + colb) = of;
      }
    }
  }
}

// ---------------- fused attention: no-max softmax, prefetched K/V ----------
__global__ __launch_bounds__(128) void attn_kernel(
    const unsigned short* __restrict__ qbuf,  // [2048][1024]
    const unsigned short* __restrict__ kbuf,  // [2048][1024]
    const unsigned short* __restrict__ vT,    // [32][64][1024]
    float* __restrict__ o32) {                // [2048][1024]
  constexpr int LD = 72;
  __shared__ __align__(16) unsigned short sP[2 * 16 * LD];
  const int bid = blockIdx.x;
  const int bh = bid & 31, qt = bid >> 5;
  const int b = bh >> 4, h = bh & 15;
  const int tid = threadIdx.x, lane = tid & 63, w = tid >> 6;
  const int l16 = lane & 15, lhi = lane >> 4;
  const int base = b * S_;
  const int qrow = qt * 32 + w * 16 + l16;

  bf16x8 aq[2];
#pragma unroll
  for (int ks = 0; ks < 2; ks++)
    aq[ks] = *(const bf16x8*)(qbuf + (size_t)(base + qrow) * 1024 + h * 64 + ks * 32 + (lhi << 3));

  f32x4 oacc[4] = {};
  float psum[4] = {0.f, 0.f, 0.f, 0.f};
  const int srow = qt * 32 + w * 16 + (lhi << 2);
  const int t0s = (qt == 31) ? 0 : ((qt >> 1) << 6);

  unsigned short* sPw = sP + w * 16 * LD;

  bf16x8 kA[8], vA[8], kB[8], vB[8];

  auto loadKV = [&](int t0, bf16x8* kd, bf16x8* vd) {
#pragma unroll
    for (int nt = 0; nt < 4; nt++) {
#pragma unroll
      for (int ks = 0; ks < 2; ks++) {
        kd[nt * 2 + ks] = *(const bf16x8*)(kbuf + (size_t)(base + t0 + nt * 16 + l16) * 1024 +
                                           h * 64 + ks * 32 + (lhi << 3));
        vd[nt * 2 + ks] = *(const bf16x8*)(vT + (size_t)(bh * 64 + nt * 16 + l16) * 1024 +
                                           t0 + ks * 32 + (lhi << 3));
      }
    }
  };

  auto compute = [&](int t0, const bf16x8* kc, const bf16x8* vc) {
    f32x4 sacc[4] = {};
#pragma unroll
    for (int ks = 0; ks < 2; ks++)
#pragma unroll
      for (int nt = 0; nt < 4; nt++)
        sacc[nt] = __builtin_amdgcn_mfma_f32_16x16x32_bf16(aq[ks], kc[nt * 2 + ks], sacc[nt], 0, 0, 0);
#pragma unroll
    for (int nt = 0; nt < 4; nt++) {
      int tcol = t0 + nt * 16 + l16;
#pragma unroll
      for (int r = 0; r < 4; r++) {
        const int row = srow + r;
        float e;
        if (row == S_ - 1)      e = 1.f;
        else if (tcol <= row)   e = 0.f;
        else                    e = __expf(fminf(sacc[nt][r] * 0.125f, 60.f));
        psum[r] += e;
        sPw[((lhi << 2) + r) * LD + nt * 16 + l16] = f2b(e);
      }
    }
#pragma unroll
    for (int ks = 0; ks < 2; ks++) {
      bf16x8 ap = *(const bf16x8*)(sPw + l16 * LD + ks * 32 + (lhi << 3));
#pragma unroll
      for (int nt = 0; nt < 4; nt++)
        oacc[nt] = __builtin_amdgcn_mfma_f32_16x16x32_bf16(ap, vc[nt * 2 + ks], oacc[nt], 0, 0, 0);
    }
  };

  loadKV(t0s, kA, vA);
  int t0 = t0s;
  while (true) {
    if (t0 + 64 < S_) loadKV(t0 + 64, kB, vB);
    compute(t0, kA, vA);
    t0 += 64; if (t0 >= S_) break;
    if (t0 + 64 < S_) loadKV(t0 + 64, kA, vA);
    compute(t0, kB, vB);
    t0 += 64; if (t0 >= S_) break;
  }

  float lrun[4];
#pragma unroll
  for (int r = 0; r < 4; r++) {
    float rs = psum[r];
#pragma unroll
    for (int off = 1; off < 16; off <<= 1) rs += __shfl_xor(rs, off, 16);
    lrun[r] = rs;
  }
#pragma unroll
  for (int nt = 0; nt < 4; nt++) {
#pragma unroll
    for (int r = 0; r < 4; r++) {
      int row = srow + r;
      o32[(size_t)(base + row) * 1024 + h * 64 + nt * 16 + l16] = oacc[nt][r] / lrun[r];
    }
  }
}

// ---------------- residual + LayerNorm -> bf16 ----------------
__global__ __launch_bounds__(256) void ln_kernel(
    const float* __restrict__ x32, const float* __restrict__ o32,
    const float* __restrict__ lnw, const float* __restrict__ lnb,
    unsigned short* __restrict__ yn) {
  __shared__ float red[8];
  const int row = blockIdx.x, tid = threadIdx.x;
  const int lane = tid & 63, wave = tid >> 6;
  const int e0 = tid * 4;
  float4 xv = *(const float4*)(x32 + (size_t)row * E_ + e0);
  float4 ov = *(const float4*)(o32 + (size_t)row * E_ + e0);
  float y0 = xv.x + ov.x, y1 = xv.y + ov.y, y2 = xv.z + ov.z, y3 = xv.w + ov.w;
  float s = y0 + y1 + y2 + y3;
  float sq = y0 * y0 + y1 * y1 + y2 * y2 + y3 * y3;
#pragma unroll
  for (int off = 32; off > 0; off >>= 1) {
    s += __shfl_xor(s, off, 64);
    sq += __shfl_xor(sq, off, 64);
  }
  if (lane == 0) { red[wave * 2] = s; red[wave * 2 + 1] = sq; }
  __syncthreads();
  float ts = red[0] + red[2] + red[4] + red[6];
  float tsq = red[1] + red[3] + red[5] + red[7];
  float mu = ts * (1.f / E_);
  float var = tsq * (1.f / E_) - mu * mu;
  float rstd = rsqrtf(var + 1e-5f);
  float4 gv = *(const float4*)(lnw + e0);
  float4 bv = *(const float4*)(lnb + e0);
  ushort4 o;
  o.x = f2b((y0 - mu) * rstd * gv.x + bv.x);
  o.y = f2b((y1 - mu) * rstd * gv.y + bv.y);
  o.z = f2b((y2 - mu) * rstd * gv.z + bv.z);
  o.w = f2b((y3 - mu) * rstd * gv.w + bv.w);
  *(ushort4*)(yn + (size_t)row * E_ + e0) = o;
}

// ---------------------------------------------------------------------------
extern "C" void kernel_launch(void* const* d_in, const int* in_sizes, int n_in,
                              void* d_out, int out_size, void* d_ws, size_t ws_size,
                              hipStream_t stream) {
  const int* tokens  = (const int*)d_in[0];
  const float* emb   = (const float*)d_in[1];
  const float* pe    = (const float*)d_in[2];
  const float* k1w   = (const float*)d_in[3];
  const float* k1b   = (const float*)d_in[4];
  const float* k2w   = (const float*)d_in[5];
  const float* k2b   = (const float*)d_in[6];
  const float* q1w   = (const float*)d_in[7];
  const float* q1b   = (const float*)d_in[8];
  const float* q2w   = (const float*)d_in[9];
  const float* q2b   = (const float*)d_in[10];
  const float* vw    = (const float*)d_in[11];
  const float* vb    = (const float*)d_in[12];
  const float* lnw   = (const float*)d_in[13];
  const float* lnb   = (const float*)d_in[14];
  const float* p1w   = (const float*)d_in[15];
  const float* p1b   = (const float*)d_in[16];
  const float* p2w   = (const float*)d_in[17];
  const float* p2b   = (const float*)d_in[18];
  const float* predw = (const float*)d_in[19];
  const float* predb = (const float*)d_in[20];
  float* out = (float*)d_out;

  // -------- workspace carve --------
  char* p = (char*)d_ws;
  auto alloc = [&](size_t bytes) -> char* {
    char* r = p; p += (bytes + 255) & ~(size_t)255; return r;
  };
  unsigned short* wk2   = (unsigned short*)alloc((size_t)L_ * H_ * 64 * 64 * 2);
  unsigned short* wq2   = (unsigned short*)alloc((size_t)L_ * H_ * 64 * 64 * 2);
  unsigned short* wpred = (unsigned short*)alloc((size_t)V_ * 1024 * 2);
  float*          bcat  = (float*)alloc((size_t)L_ * 3072 * 4);
  float*          x32   = (float*)alloc((size_t)M_ * 1024 * 4);
  unsigned short* xb    = (unsigned short*)alloc((size_t)M_ * 1024 * 2);
  unsigned short* kbuf  = (unsigned short*)alloc((size_t)M_ * 1024 * 2);
  unsigned short* qbuf  = (unsigned short*)alloc((size_t)M_ * 1024 * 2);
  unsigned short* vTb   = (unsigned short*)alloc((size_t)32 * 64 * 1024 * 2);
  float*          o32   = (float*)alloc((size_t)M_ * 1024 * 4);
  unsigned short* yn    = (unsigned short*)alloc((size_t)M_ * 1024 * 2);
  unsigned short* h1    = (unsigned short*)alloc((size_t)M_ * 1024 * 2);
  if ((size_t)(p - (char*)d_ws) > ws_size) return;

  // -------- small conversions (k2, q2, predw) + bias concat --------
  cvt3_kernel<<<33024, 256, 0, stream>>>(k2w, q2w, predw, wk2, wq2, wpred);
  biascat_kernel<<<96, 256, 0, stream>>>(k1b, q1b, vb, bcat);

  // -------- embedding --------
  embed_kernel<<<M_, 256, 0, stream>>>(tokens, emb, pe, x32, xb);

  // -------- layers --------
  for (int l = 0; l < L_; l++) {
    const float* k1w_l = k1w + (size_t)l * 1048576;
    const float* q1w_l = q1w + (size_t)l * 1048576;
    const float* vw_l  = vw  + (size_t)l * 1048576;
    const float* bcat_l = bcat + (size_t)l * 3072;
    const unsigned short* wk2_l = wk2 + (size_t)l * H_ * 64 * 64;
    const unsigned short* wq2_l = wq2 + (size_t)l * H_ * 64 * 64;
    const float* wp1_l = p1w + (size_t)l * 1048576;
    const float* wp2_l = p2w + (size_t)l * 1048576;

    // fused kqv + k2q2: k/q blocks -> kbuf/qbuf, v blocks -> vT (fp32 weights)
    gemm97<128, 128, 2, 0, 0, 1, 1><<<dim3(16, 24), 256, 0, stream>>>(
        xb, k1w_l, q1w_l, vw_l, bcat_l, nullptr, nullptr, vTb,
        wk2_l, wq2_l, k2b + l * 1024, q2b + l * 1024, kbuf, qbuf, 1024, 3072, 2048);
    attn_kernel<<<1024, 128, 0, stream>>>(qbuf, kbuf, vTb, o32);
    ln_kernel<<<M_, 256, 0, stream>>>(x32, o32, lnw + l * 1024, lnb + l * 1024, yn);
    gemm97<64, 64, 1, 1, 0, 0, 0><<<dim3(32, 16), 256, 0, stream>>>(
        yn, wp1_l, wp1_l, wp1_l, p1b + l * 1024, h1, nullptr, nullptr,
        nullptr, nullptr, nullptr, nullptr, nullptr, nullptr, 1024, 1024, 0);
    gemm97<64, 64, 1, 1, 1, 0, 0><<<dim3(32, 16), 256, 0, stream>>>(
        h1, wp2_l, wp2_l, wp2_l, p2b + l * 1024, xb, x32, nullptr,
        nullptr, nullptr, nullptr, nullptr, nullptr, nullptr, 1024, 1024, 0);
  }

  // -------- vocab projection: 4-phase/K-tile template --------
  gemm256_8p<<<1000, 512, 0, stream>>>(xb, wpred, predb, out);
}

// Round 12
// 1330.894 us; speedup vs baseline: 1.1430x; 1.1430x over previous
//
#include <hip/hip_runtime.h>

// ---------------------------------------------------------------------------
// Transformer forward, MI355X gfx950. bf16 MFMA compute, fp32 accum/output.
//   activations: row = b*S + s (M = 2048 rows)
//   vT buffer:   [32 bh][64 d][1024 t] bf16 (V transposed, written by kqv GEMM)
// kqv GEMM fuses the per-head K2/Q2 second MLP. All weights pre-converted to
// bf16 (cvt_all). Layer GEMMs: m97 structure, glds staging, chunk-XOR swizzle.
// MLP GEMMs: 64x64 tile, 512 blocks (2 blocks/CU). Vocab GEMM: 256x256 BK=64
// 4-phase template, counted vmcnt, conflict-free swizzle.
// Attention: no-max softmax + K/V register double-buffer.
// ---------------------------------------------------------------------------

typedef __attribute__((ext_vector_type(8))) short bf16x8;
typedef __attribute__((ext_vector_type(4))) float f32x4;

#define L_ 8
#define S_ 1024
#define E_ 1024
#define B_ 2
#define H_ 16
#define V_ 32000
#define M_ 2048  // B*S

__device__ __forceinline__ unsigned short f2b(float f) {
  union { float f; unsigned int u; } v; v.f = f;
  unsigned int r = v.u + 0x7FFFu + ((v.u >> 16) & 1u);
  return (unsigned short)(r >> 16);
}

#define GLDS16(gptr, lptr)                                                            \
  __builtin_amdgcn_global_load_lds(                                                   \
      (const __attribute__((address_space(1))) unsigned int*)(gptr),                  \
      (__attribute__((address_space(3))) unsigned int*)(lptr), 16, 0, 0)

// ---------------- fused weight conversion (all fp32 weights -> bf16) -------
__global__ void cvt_all_kernel(
    const float* __restrict__ k1w, const float* __restrict__ q1w,
    const float* __restrict__ vw,  const float* __restrict__ k2w,
    const float* __restrict__ q2w, const float* __restrict__ p1w,
    const float* __restrict__ p2w, const float* __restrict__ predw,
    unsigned short* __restrict__ wcat, unsigned short* __restrict__ wk2,
    unsigned short* __restrict__ wq2,  unsigned short* __restrict__ wp1,
    unsigned short* __restrict__ wp2,  unsigned short* __restrict__ wpred) {
  size_t u = (size_t)blockIdx.x * 256 + threadIdx.x;
  const float* src; unsigned short* dst;
  if (u < 6291456) {            // k1 | q1 | v  -> wcat (per-layer interleave)
    int seg = (int)(u / 2097152);
    size_t e0 = (u - (size_t)seg * 2097152) * 4;
    const float* s = (seg == 0) ? k1w : (seg == 1) ? q1w : vw;
    src = s + e0;
    int l = (int)(e0 >> 20), off = (int)(e0 & 1048575);
    dst = wcat + (size_t)l * 3145728 + (size_t)seg * 1048576 + off;
  } else if (u < 6422528) { size_t e = (u - 6291456) * 4;  src = k2w + e;   dst = wk2 + e; }
  else if (u < 6553600)   { size_t e = (u - 6422528) * 4;  src = q2w + e;   dst = wq2 + e; }
  else if (u < 8650752)   { size_t e = (u - 6553600) * 4;  src = p1w + e;   dst = wp1 + e; }
  else if (u < 10747904)  { size_t e = (u - 8650752) * 4;  src = p2w + e;   dst = wp2 + e; }
  else                    { size_t e = (u - 10747904) * 4; src = predw + e; dst = wpred + e; }
  float4 v = *(const float4*)src;
  dst[0] = f2b(v.x); dst[1] = f2b(v.y); dst[2] = f2b(v.z); dst[3] = f2b(v.w);
}

__global__ void biascat_kernel(const float* __restrict__ k1b, const float* __restrict__ q1b,
                               const float* __restrict__ vb, float* __restrict__ bcat) {
  int i = blockIdx.x * 256 + threadIdx.x;  // 8*3072 exact
  int l = i / 3072, j = i - l * 3072;
  float v;
  if (j < 1024)      v = k1b[l * 1024 + j];
  else if (j < 2048) v = q1b[l * 1024 + j - 1024];
  else               v = vb [l * 1024 + j - 2048];
  bcat[i] = v;
}

// ---------------- embedding ----------------
__global__ void embed_kernel(const int* __restrict__ tokens, const float* __restrict__ emb,
                             const float* __restrict__ pe, float* __restrict__ x32,
                             unsigned short* __restrict__ xb) {
  int row = blockIdx.x;           // b*S + s
  int s = row & (S_ - 1);
  int e0 = threadIdx.x * 4;
  int tok = tokens[row];
  float4 ev = *(const float4*)(emb + (size_t)tok * E_ + e0);
  float4 pv = *(const float4*)(pe + (size_t)s * E_ + e0);
  float4 v; v.x = ev.x + pv.x; v.y = ev.y + pv.y; v.z = ev.z + pv.z; v.w = ev.w + pv.w;
  *(float4*)(x32 + (size_t)row * E_ + e0) = v;
  ushort4 o; o.x = f2b(v.x); o.y = f2b(v.y); o.z = f2b(v.z); o.w = f2b(v.w);
  *(ushort4*)(xb + (size_t)row * E_ + e0) = o;
}

// ---------------- m97-style GEMM: C = act(A * W^T + bias) ----------------
// K2Q2: blocks with col0<2048 route their relu'd output through LDS into the
// per-head second MLP (k2/q2), writing kbuf/qbuf instead of Cb.
template <int BM, int BN, int RELU, int OBF, int OF32, int VT, int K2Q2>
__global__ __launch_bounds__(256) void gemm97(
    const unsigned short* __restrict__ A, const unsigned short* __restrict__ W,
    const float* __restrict__ bias, unsigned short* __restrict__ Cb,
    float* __restrict__ Cf, unsigned short* __restrict__ vTp,
    const unsigned short* __restrict__ wk2p, const unsigned short* __restrict__ wq2p,
    const float* __restrict__ k2bp, const float* __restrict__ q2bp,
    unsigned short* __restrict__ kbufp, unsigned short* __restrict__ qbufp,
    int K, int N, int reluN) {
  constexpr int AR = BM / 64;
  constexpr int BR = BN / 64;
  constexpr int FM = BM / 32;
  constexpr int FN = BN / 32;
  __shared__ __align__(16) unsigned short sA[BM * 32];
  __shared__ __align__(16) unsigned short sB[BN * 32];
  __shared__ __align__(16) unsigned short sC[K2Q2 ? 128 * 136 : 1];  // padded
  const int tid = threadIdx.x;
  const int lane = tid & 63, wave = tid >> 6;
  const int l16 = lane & 15, lhi = lane >> 4;

  const int gx = gridDim.x, nwg = gx * gridDim.y;
  int o = blockIdx.y * gx + blockIdx.x;
  int wg = ((nwg & 7) == 0) ? ((o & 7) * (nwg >> 3) + (o >> 3)) : o;
  const int row0 = (wg % gx) * BM, col0 = (wg / gx) * BN;

  const int wm = (wave >> 1) * (BM / 2), wn = (wave & 1) * (BN / 2);

  const int srow = wave * 16 + (lane >> 2);
  const int scol = ((lane & 3) ^ ((lane >> 3) & 3)) * 8;   // chunk ^ ((row>>1)&3)
  const int cx = (lhi ^ ((l16 >> 1) & 3)) * 8;

  f32x4 acc[FM][FN] = {};

  for (int k0 = 0; k0 < K; k0 += 32) {
#pragma unroll
    for (int r = 0; r < AR; r++)
      GLDS16(A + (size_t)(row0 + r * 64 + srow) * K + k0 + scol,
             sA + r * 2048 + wave * 512);
#pragma unroll
    for (int r = 0; r < BR; r++)
      GLDS16(W + (size_t)(col0 + r * 64 + srow) * K + k0 + scol,
             sB + r * 2048 + wave * 512);
    __syncthreads();

    bf16x8 af[FM], bf[FN];
#pragma unroll
    for (int i = 0; i < FM; i++)
      af[i] = *(const bf16x8*)(sA + (wm + i * 16 + l16) * 32 + cx);
#pragma unroll
    for (int j = 0; j < FN; j++)
      bf[j] = *(const bf16x8*)(sB + (wn + j * 16 + l16) * 32 + cx);
#pragma unroll
    for (int i = 0; i < FM; i++)
#pragma unroll
      for (int j = 0; j < FN; j++)
        acc[i][j] = __builtin_amdgcn_mfma_f32_16x16x32_bf16(bf[j], af[i], acc[i][j], 0, 0, 0);
    __syncthreads();
  }

  if (K2Q2 && col0 < 2048) {
    // ---- stage relu'd k1/q1 output into padded LDS ----
#pragma unroll
    for (int j = 0; j < FN; j++) {
      const int colb = wn + j * 16 + lhi * 4;
      const float4 bv = *(const float4*)(bias + col0 + colb);
#pragma unroll
      for (int i = 0; i < FM; i++) {
        const int lrow = wm + i * 16 + l16;
        ushort4 ob;
        ob.x = f2b(fmaxf(acc[i][j][0] + bv.x, 0.f));
        ob.y = f2b(fmaxf(acc[i][j][1] + bv.y, 0.f));
        ob.z = f2b(fmaxf(acc[i][j][2] + bv.z, 0.f));
        ob.w = f2b(fmaxf(acc[i][j][3] + bv.w, 0.f));
        *(ushort4*)(sC + lrow * 136 + colb) = ob;
      }
    }
    __syncthreads();
    // ---- per-head second MLP: wave (wave>>1) rows, head (wave&1) ----
    const int which = (col0 >= 1024) ? 1 : 0;
    const int h = ((col0 & 1023) >> 6) + (wave & 1);
    const unsigned short* W2 = (which ? wq2p : wk2p) + h * 4096;
    const float* b2 = (which ? q2bp : k2bp) + h * 64;
    unsigned short* outp = (which ? qbufp : kbufp) + h * 64;
    const int r0 = (wave >> 1) * 64;
    f32x4 acc2[4][4] = {};
#pragma unroll
    for (int ks = 0; ks < 2; ks++) {
      bf16x8 bfr[4], af2[4];
#pragma unroll
      for (int j = 0; j < 4; j++)
        bfr[j] = *(const bf16x8*)(W2 + (j * 16 + l16) * 64 + ks * 32 + (lhi << 3));
#pragma unroll
      for (int i = 0; i < 4; i++)
        af2[i] = *(const bf16x8*)(sC + (r0 + i * 16 + l16) * 136 + (wave & 1) * 64 +
                                  ks * 32 + (lhi << 3));
#pragma unroll
      for (int i = 0; i < 4; i++)
#pragma unroll
        for (int j = 0; j < 4; j++)
          acc2[i][j] = __builtin_amdgcn_mfma_f32_16x16x32_bf16(bfr[j], af2[i], acc2[i][j], 0, 0, 0);
    }
#pragma unroll
    for (int j = 0; j < 4; j++) {
      const float4 bv = *(const float4*)(b2 + j * 16 + lhi * 4);
#pragma unroll
      for (int i = 0; i < 4; i++) {
        const int row = row0 + r0 + i * 16 + l16;
        ushort4 ob;
        ob.x = f2b(fmaxf(acc2[i][j][0] + bv.x, 0.f));
        ob.y = f2b(fmaxf(acc2[i][j][1] + bv.y, 0.f));
        ob.z = f2b(fmaxf(acc2[i][j][2] + bv.z, 0.f));
        ob.w = f2b(fmaxf(acc2[i][j][3] + bv.w, 0.f));
        *(ushort4*)(outp + (size_t)row * 1024 + j * 16 + lhi * 4) = ob;
      }
    }
  } else {
#pragma unroll
    for (int j = 0; j < FN; j++) {
      const int colb = col0 + wn + j * 16 + lhi * 4;
      const float4 bv = *(const float4*)(bias + colb);
      const bool dorelu = (RELU == 1) || (RELU == 2 && colb < reluN);
#pragma unroll
      for (int i = 0; i < FM; i++) {
        const int row = row0 + wm + i * 16 + l16;
        float v0 = acc[i][j][0] + bv.x, v1 = acc[i][j][1] + bv.y;
        float v2 = acc[i][j][2] + bv.z, v3 = acc[i][j][3] + bv.w;
        if (dorelu) {
          v0 = fmaxf(v0, 0.f); v1 = fmaxf(v1, 0.f);
          v2 = fmaxf(v2, 0.f); v3 = fmaxf(v3, 0.f);
        }
        if (OBF) {
          ushort4 ob; ob.x = f2b(v0); ob.y = f2b(v1); ob.z = f2b(v2); ob.w = f2b(v3);
          *(ushort4*)(Cb + (size_t)row * N + colb) = ob;
        }
        if (OF32) {
          float4 of; of.x = v0; of.y = v1; of.z = v2; of.w = v3;
          *(float4*)(Cf + (size_t)row * N + colb) = of;
        }
        if (VT) {
          if (colb - lhi * 4 >= 2048) {
            const int hd0 = colb - 2048;
            const int bq = row >> 10, s = row & 1023;
            unsigned short* vr = vTp + ((size_t)(bq << 10) + hd0) * 1024 + s;
            vr[0] = f2b(v0); vr[1024] = f2b(v1); vr[2048] = f2b(v2); vr[3072] = f2b(v3);
          }
        }
      }
    }
  }
}

// ---------------- vocab GEMM: 256x256, BK=64, 4-phase/K-tile template -------
__global__ __launch_bounds__(512, 1) void gemm256_8p(
    const unsigned short* __restrict__ A, const unsigned short* __restrict__ W,
    const float* __restrict__ bias, float* __restrict__ Cf) {
  constexpr int NT = 16;               // K=1024 / BK=64
  __shared__ __align__(16) unsigned short sA[2][2][8192];
  __shared__ __align__(16) unsigned short sB[2][2][8192];
  const int tid = threadIdx.x;
  const int lane = tid & 63, wave = tid >> 6;
  const int l16 = lane & 15, lhi = lane >> 4;
  const int wr = wave >> 2, wc = wave & 3;   // 2 x 4 wave grid, tile 128x64

  const int o = blockIdx.x;
  const int wg = (o & 7) * 125 + (o >> 3);   // bijective XCD chunking
  const int row0 = (wg & 7) * 256;
  const int col0 = (wg >> 3) * 256;

  const int srow = tid >> 2;                              // staging row (128)
  const int sk   = ((tid & 3) ^ ((tid >> 3) & 3)) * 8;    // chunk ^ ((row>>1)&3)
  const int rsw  = (l16 >> 1) & 3;                        // read-side row bits

  f32x4 acc[2][4][4] = {};

  auto stageA = [&](int kt, int s) {
    const int buf = kt & 1;
    const int kg = kt * 64 + s * 32 + sk;
#pragma unroll
    for (int i = 0; i < 2; i++)
      GLDS16(A + (size_t)(row0 + i * 128 + srow) * 1024 + kg,
             &sA[buf][s][i * 4096 + wave * 512]);
  };
  auto stageB = [&](int kt, int s) {
    const int buf = kt & 1;
    const int kg = kt * 64 + s * 32 + sk;
#pragma unroll
    for (int i = 0; i < 2; i++)
      GLDS16(W + (size_t)(col0 + i * 128 + srow) * 1024 + kg,
             &sB[buf][s][i * 4096 + wave * 512]);
  };

  stageA(0, 0); stageB(0, 0); stageA(0, 1); stageB(0, 1);

  bf16x8 af[4], bf[4];
  for (int kt = 0; kt < NT; kt++) {
    const int buf = kt & 1;
    const bool more = (kt + 1 < NT);

    // ---- phase 0: (rh0, ks0) ----
    asm volatile("s_waitcnt vmcnt(4)" ::: "memory");
    __builtin_amdgcn_s_barrier();
    __builtin_amdgcn_sched_barrier(0);
#pragma unroll
    for (int j = 0; j < 4; j++)
      bf[j] = *(const bf16x8*)(&sB[buf][0][(wc * 64 + j * 16 + l16) * 32 + ((lhi ^ rsw) << 3)]);
#pragma unroll
    for (int i = 0; i < 4; i++)
      af[i] = *(const bf16x8*)(&sA[buf][0][(wr * 128 + i * 16 + l16) * 32 + ((lhi ^ rsw) << 3)]);
    if (more) stageA(kt + 1, 0);
    asm volatile("s_waitcnt lgkmcnt(0)" ::: "memory");
    __builtin_amdgcn_sched_barrier(0);
    __builtin_amdgcn_s_setprio(1);
#pragma unroll
    for (int i = 0; i < 4; i++)
#pragma unroll
      for (int j = 0; j < 4; j++)
        acc[0][i][j] = __builtin_amdgcn_mfma_f32_16x16x32_bf16(bf[j], af[i], acc[0][i][j], 0, 0, 0);
    __builtin_amdgcn_s_setprio(0);
    __builtin_amdgcn_s_barrier();

    // ---- phase 1: (rh1, ks0) ----
#pragma unroll
    for (int i = 0; i < 4; i++)
      af[i] = *(const bf16x8*)(&sA[buf][0][(wr * 128 + 64 + i * 16 + l16) * 32 + ((lhi ^ rsw) << 3)]);
    if (more) stageB(kt + 1, 0);
    asm volatile("s_waitcnt lgkmcnt(0)" ::: "memory");
    __builtin_amdgcn_sched_barrier(0);
    __builtin_amdgcn_s_setprio(1);
#pragma unroll
    for (int i = 0; i < 4; i++)
#pragma unroll
      for (int j = 0; j < 4; j++)
        acc[1][i][j] = __builtin_amdgcn_mfma_f32_16x16x32_bf16(bf[j], af[i], acc[1][i][j], 0, 0, 0);
    __builtin_amdgcn_s_setprio(0);
    __builtin_amdgcn_s_barrier();

    // ---- phase 2: (rh0, ks1) ----
    if (kt == NT - 1) { asm volatile("s_waitcnt vmcnt(0)" ::: "memory"); }
    else              { asm volatile("s_waitcnt vmcnt(4)" ::: "memory"); }
    __builtin_amdgcn_s_barrier();
    __builtin_amdgcn_sched_barrier(0);
#pragma unroll
    for (int j = 0; j < 4; j++)
      bf[j] = *(const bf16x8*)(&sB[buf][1][(wc * 64 + j * 16 + l16) * 32 + ((lhi ^ rsw) << 3)]);
#pragma unroll
    for (int i = 0; i < 4; i++)
      af[i] = *(const bf16x8*)(&sA[buf][1][(wr * 128 + i * 16 + l16) * 32 + ((lhi ^ rsw) << 3)]);
    if (more) stageA(kt + 1, 1);
    asm volatile("s_waitcnt lgkmcnt(0)" ::: "memory");
    __builtin_amdgcn_sched_barrier(0);
    __builtin_amdgcn_s_setprio(1);
#pragma unroll
    for (int i = 0; i < 4; i++)
#pragma unroll
      for (int j = 0; j < 4; j++)
        acc[0][i][j] = __builtin_amdgcn_mfma_f32_16x16x32_bf16(bf[j], af[i], acc[0][i][j], 0, 0, 0);
    __builtin_amdgcn_s_setprio(0);
    __builtin_amdgcn_s_barrier();

    // ---- phase 3: (rh1, ks1) ----
#pragma unroll
    for (int i = 0; i < 4; i++)
      af[i] = *(const bf16x8*)(&sA[buf][1][(wr * 128 + 64 + i * 16 + l16) * 32 + ((lhi ^ rsw) << 3)]);
    if (more) stageB(kt + 1, 1);
    asm volatile("s_waitcnt lgkmcnt(0)" ::: "memory");
    __builtin_amdgcn_sched_barrier(0);
    __builtin_amdgcn_s_setprio(1);
#pragma unroll
    for (int i = 0; i < 4; i++)
#pragma unroll
      for (int j = 0; j < 4; j++)
        acc[1][i][j] = __builtin_amdgcn_mfma_f32_16x16x32_bf16(bf[j], af[i], acc[1][i][j], 0, 0, 0);
    __builtin_amdgcn_s_setprio(0);
    __builtin_amdgcn_s_barrier();
  }

#pragma unroll
  for (int rh = 0; rh < 2; rh++) {
#pragma unroll
    for (int j = 0; j < 4; j++) {
      const int colb = col0 + wc * 64 + j * 16 + lhi * 4;
      const float4 bv = *(const float4*)(bias + colb);
#pragma unroll
      for (int i = 0; i < 4; i++) {
        const int row = row0 + wr * 128 + rh * 64 + i * 16 + l16;
        float4 of;
        of.x = acc[rh][i][j][0] + bv.x; of.y = acc[rh][i][j][1] + bv.y;
        of.z = acc[rh][i][j][2] + bv.z; of.w = acc[rh][i][j][3] + bv.w;
        *(float4*)(Cf + (size_t)row * V_ + colb) = of;
      }
    }
  }
}

// ---------------- fused attention: no-max softmax, prefetched K/V ----------
__global__ __launch_bounds__(128) void attn_kernel(
    const unsigned short* __restrict__ qbuf,  // [2048][1024]
    const unsigned short* __restrict__ kbuf,  // [2048][1024]
    const unsigned short* __restrict__ vT,    // [32][64][1024]
    float* __restrict__ o32) {                // [2048][1024]
  constexpr int LD = 72;
  __shared__ __align__(16) unsigned short sP[2 * 16 * LD];
  const int bid = blockIdx.x;
  const int bh = bid & 31, qt = bid >> 5;
  const int b = bh >> 4, h = bh & 15;
  const int tid = threadIdx.x, lane = tid & 63, w = tid >> 6;
  const int l16 = lane & 15, lhi = lane >> 4;
  const int base = b * S_;
  const int qrow = qt * 32 + w * 16 + l16;

  bf16x8 aq[2];
#pragma unroll
  for (int ks = 0; ks < 2; ks++)
    aq[ks] = *(const bf16x8*)(qbuf + (size_t)(base + qrow) * 1024 + h * 64 + ks * 32 + (lhi << 3));

  f32x4 oacc[4] = {};
  float psum[4] = {0.f, 0.f, 0.f, 0.f};
  const int srow = qt * 32 + w * 16 + (lhi << 2);
  const int t0s = (qt == 31) ? 0 : ((qt >> 1) << 6);

  unsigned short* sPw = sP + w * 16 * LD;

  bf16x8 kA[8], vA[8], kB[8], vB[8];

  auto loadKV = [&](int t0, bf16x8* kd, bf16x8* vd) {
#pragma unroll
    for (int nt = 0; nt < 4; nt++) {
#pragma unroll
      for (int ks = 0; ks < 2; ks++) {
        kd[nt * 2 + ks] = *(const bf16x8*)(kbuf + (size_t)(base + t0 + nt * 16 + l16) * 1024 +
                                           h * 64 + ks * 32 + (lhi << 3));
        vd[nt * 2 + ks] = *(const bf16x8*)(vT + (size_t)(bh * 64 + nt * 16 + l16) * 1024 +
                                           t0 + ks * 32 + (lhi << 3));
      }
    }
  };

  auto compute = [&](int t0, const bf16x8* kc, const bf16x8* vc) {
    f32x4 sacc[4] = {};
#pragma unroll
    for (int ks = 0; ks < 2; ks++)
#pragma unroll
      for (int nt = 0; nt < 4; nt++)
        sacc[nt] = __builtin_amdgcn_mfma_f32_16x16x32_bf16(aq[ks], kc[nt * 2 + ks], sacc[nt], 0, 0, 0);
#pragma unroll
    for (int nt = 0; nt < 4; nt++) {
      int tcol = t0 + nt * 16 + l16;
#pragma unroll
      for (int r = 0; r < 4; r++) {
        const int row = srow + r;
        float e;
        if (row == S_ - 1)      e = 1.f;
        else if (tcol <= row)   e = 0.f;
        else                    e = __expf(fminf(sacc[nt][r] * 0.125f, 60.f));
        psum[r] += e;
        sPw[((lhi << 2) + r) * LD + nt * 16 + l16] = f2b(e);
      }
    }
#pragma unroll
    for (int ks = 0; ks < 2; ks++) {
      bf16x8 ap = *(const bf16x8*)(sPw + l16 * LD + ks * 32 + (lhi << 3));
#pragma unroll
      for (int nt = 0; nt < 4; nt++)
        oacc[nt] = __builtin_amdgcn_mfma_f32_16x16x32_bf16(ap, vc[nt * 2 + ks], oacc[nt], 0, 0, 0);
    }
  };

  loadKV(t0s, kA, vA);
  int t0 = t0s;
  while (true) {
    if (t0 + 64 < S_) loadKV(t0 + 64, kB, vB);
    compute(t0, kA, vA);
    t0 += 64; if (t0 >= S_) break;
    if (t0 + 64 < S_) loadKV(t0 + 64, kA, vA);
    compute(t0, kB, vB);
    t0 += 64; if (t0 >= S_) break;
  }

  float lrun[4];
#pragma unroll
  for (int r = 0; r < 4; r++) {
    float rs = psum[r];
#pragma unroll
    for (int off = 1; off < 16; off <<= 1) rs += __shfl_xor(rs, off, 16);
    lrun[r] = rs;
  }
#pragma unroll
  for (int nt = 0; nt < 4; nt++) {
#pragma unroll
    for (int r = 0; r < 4; r++) {
      int row = srow + r;
      o32[(size_t)(base + row) * 1024 + h * 64 + nt * 16 + l16] = oacc[nt][r] / lrun[r];
    }
  }
}

// ---------------- residual + LayerNorm -> bf16 ----------------
__global__ __launch_bounds__(256) void ln_kernel(
    const float* __restrict__ x32, const float* __restrict__ o32,
    const float* __restrict__ lnw, const float* __restrict__ lnb,
    unsigned short* __restrict__ yn) {
  __shared__ float red[8];
  const int row = blockIdx.x, tid = threadIdx.x;
  const int lane = tid & 63, wave = tid >> 6;
  const int e0 = tid * 4;
  float4 xv = *(const float4*)(x32 + (size_t)row * E_ + e0);
  float4 ov = *(const float4*)(o32 + (size_t)row * E_ + e0);
  float y0 = xv.x + ov.x, y1 = xv.y + ov.y, y2 = xv.z + ov.z, y3 = xv.w + ov.w;
  float s = y0 + y1 + y2 + y3;
  float sq = y0 * y0 + y1 * y1 + y2 * y2 + y3 * y3;
#pragma unroll
  for (int off = 32; off > 0; off >>= 1) {
    s += __shfl_xor(s, off, 64);
    sq += __shfl_xor(sq, off, 64);
  }
  if (lane == 0) { red[wave * 2] = s; red[wave * 2 + 1] = sq; }
  __syncthreads();
  float ts = red[0] + red[2] + red[4] + red[6];
  float tsq = red[1] + red[3] + red[5] + red[7];
  float mu = ts * (1.f / E_);
  float var = tsq * (1.f / E_) - mu * mu;
  float rstd = rsqrtf(var + 1e-5f);
  float4 gv = *(const float4*)(lnw + e0);
  float4 bv = *(const float4*)(lnb + e0);
  ushort4 o;
  o.x = f2b((y0 - mu) * rstd * gv.x + bv.x);
  o.y = f2b((y1 - mu) * rstd * gv.y + bv.y);
  o.z = f2b((y2 - mu) * rstd * gv.z + bv.z);
  o.w = f2b((y3 - mu) * rstd * gv.w + bv.w);
  *(ushort4*)(yn + (size_t)row * E_ + e0) = o;
}

// ---------------------------------------------------------------------------
extern "C" void kernel_launch(void* const* d_in, const int* in_sizes, int n_in,
                              void* d_out, int out_size, void* d_ws, size_t ws_size,
                              hipStream_t stream) {
  const int* tokens  = (const int*)d_in[0];
  const float* emb   = (const float*)d_in[1];
  const float* pe    = (const float*)d_in[2];
  const float* k1w   = (const float*)d_in[3];
  const float* k1b   = (const float*)d_in[4];
  const float* k2w   = (const float*)d_in[5];
  const float* k2b   = (const float*)d_in[6];
  const float* q1w   = (const float*)d_in[7];
  const float* q1b   = (const float*)d_in[8];
  const float* q2w   = (const float*)d_in[9];
  const float* q2b   = (const float*)d_in[10];
  const float* vw    = (const float*)d_in[11];
  const float* vb    = (const float*)d_in[12];
  const float* lnw   = (const float*)d_in[13];
  const float* lnb   = (const float*)d_in[14];
  const float* p1w   = (const float*)d_in[15];
  const float* p1b   = (const float*)d_in[16];
  const float* p2w   = (const float*)d_in[17];
  const float* p2b   = (const float*)d_in[18];
  const float* predw = (const float*)d_in[19];
  const float* predb = (const float*)d_in[20];
  float* out = (float*)d_out;

  // -------- workspace carve --------
  char* p = (char*)d_ws;
  auto alloc = [&](size_t bytes) -> char* {
    char* r = p; p += (bytes + 255) & ~(size_t)255; return r;
  };
  unsigned short* wcat  = (unsigned short*)alloc((size_t)L_ * 3072 * 1024 * 2);
  unsigned short* wk2   = (unsigned short*)alloc((size_t)L_ * H_ * 64 * 64 * 2);
  unsigned short* wq2   = (unsigned short*)alloc((size_t)L_ * H_ * 64 * 64 * 2);
  unsigned short* wp1   = (unsigned short*)alloc((size_t)L_ * 1024 * 1024 * 2);
  unsigned short* wp2   = (unsigned short*)alloc((size_t)L_ * 1024 * 1024 * 2);
  unsigned short* wpred = (unsigned short*)alloc((size_t)V_ * 1024 * 2);
  float*          bcat  = (float*)alloc((size_t)L_ * 3072 * 4);
  float*          x32   = (float*)alloc((size_t)M_ * 1024 * 4);
  unsigned short* xb    = (unsigned short*)alloc((size_t)M_ * 1024 * 2);
  unsigned short* kbuf  = (unsigned short*)alloc((size_t)M_ * 1024 * 2);
  unsigned short* qbuf  = (unsigned short*)alloc((size_t)M_ * 1024 * 2);
  unsigned short* vTb   = (unsigned short*)alloc((size_t)32 * 64 * 1024 * 2);
  float*          o32   = (float*)alloc((size_t)M_ * 1024 * 4);
  unsigned short* yn    = (unsigned short*)alloc((size_t)M_ * 1024 * 2);
  unsigned short* h1    = (unsigned short*)alloc((size_t)M_ * 1024 * 2);
  if ((size_t)(p - (char*)d_ws) > ws_size) return;

  // -------- fused weight conversion (fp32 -> bf16), every call --------
  cvt_all_kernel<<<73984, 256, 0, stream>>>(k1w, q1w, vw, k2w, q2w, p1w, p2w, predw,
                                            wcat, wk2, wq2, wp1, wp2, wpred);
  biascat_kernel<<<96, 256, 0, stream>>>(k1b, q1b, vb, bcat);

  // -------- embedding --------
  embed_kernel<<<M_, 256, 0, stream>>>(tokens, emb, pe, x32, xb);

  // -------- layers --------
  for (int l = 0; l < L_; l++) {
    const unsigned short* wcat_l = wcat + (size_t)l * 3072 * 1024;
    const float* bcat_l = bcat + (size_t)l * 3072;
    const unsigned short* wk2_l = wk2 + (size_t)l * H_ * 64 * 64;
    const unsigned short* wq2_l = wq2 + (size_t)l * H_ * 64 * 64;
    const unsigned short* wp1_l = wp1 + (size_t)l * 1024 * 1024;
    const unsigned short* wp2_l = wp2 + (size_t)l * 1024 * 1024;

    // fused kqv + k2q2: k/q blocks -> kbuf/qbuf, v blocks -> vT
    gemm97<128, 128, 2, 0, 0, 1, 1><<<dim3(16, 24), 256, 0, stream>>>(
        xb, wcat_l, bcat_l, nullptr, nullptr, vTb,
        wk2_l, wq2_l, k2b + l * 1024, q2b + l * 1024, kbuf, qbuf, 1024, 3072, 2048);
    attn_kernel<<<1024, 128, 0, stream>>>(qbuf, kbuf, vTb, o32);
    ln_kernel<<<M_, 256, 0, stream>>>(x32, o32, lnw + l * 1024, lnb + l * 1024, yn);
    gemm97<64, 64, 1, 1, 0, 0, 0><<<dim3(32, 16), 256, 0, stream>>>(
        yn, wp1_l, p1b + l * 1024, h1, nullptr, nullptr,
        nullptr, nullptr, nullptr, nullptr, nullptr, nullptr, 1024, 1024, 0);
    gemm97<64, 64, 1, 1, 1, 0, 0><<<dim3(32, 16), 256, 0, stream>>>(
        h1, wp2_l, p2b + l * 1024, xb, x32, nullptr,
        nullptr, nullptr, nullptr, nullptr, nullptr, nullptr, 1024, 1024, 0);
  }

  // -------- vocab projection: 4-phase/K-tile template --------
  gemm256_8p<<<1000, 512, 0, stream>>>(xb, wpred, predb, out);
}